// Round 1
// baseline (207.752 us; speedup 1.0000x reference)
//
#include <hip/hip_runtime.h>

#define BB 4
#define CC 64
#define HH 128
#define WW 128
#define NN 16
#define HW (HH*WW)

__device__ __forceinline__ float softplus_f(float x) {
    float e = __expf(-fabsf(x));
    return fmaxf(x, 0.0f) + __logf(1.0f + e);
}

// Broadcast lane (quad_base + SRC) to all 4 quad lanes. Pure-VALU DPP quad_perm.
template<int SRC>
__device__ __forceinline__ float quad_bcast(float v) {
    return __int_as_float(__builtin_amdgcn_mov_dpp(
        __float_as_int(v), SRC * 0x55, 0xF, 0xF, true));
}

// ===========================================================================
// Fused proj+scan. grid 1024, block 256 = 64 d x 4 ng (4 SSM states/lane).
// Blocks [0,512): h-scan of row (b,L=h) -> out[b,c,h,:]
// Blocks [512,1024): v-scan of col (b,L=w) -> yv[b,c,w,:]  ([b][c][w][h])
// R12: line processed as 2x 64-pixel segments -> LDS 25.6 KB (6 blocks/CU
// capacity, grid's 4/CU all resident, no tail round). dlt buffer + its 32
// per-chunk barriers replaced by quad-DPP delta broadcast: scan is
// barrier-free within a segment (5 barriers/block total vs 34).
// ===========================================================================
__global__ __launch_bounds__(256) void k_scan(
    const float* __restrict__ x, const float* __restrict__ xpw,
    const float* __restrict__ A_log, const float* __restrict__ Dv,
    const float* __restrict__ dtw, const float* __restrict__ dtb,
    float* __restrict__ out, float* __restrict__ yv)
{
    __shared__ float xt[64 * 64];    // 16 KB  x half-line, (jl,c) at jl*64+((c+jl)&63)
    __shared__ float bcs[64 * 32];   //  8 KB  B/C, group g at jl*32+((g^(jl&7))<<2)
    __shared__ float dtr[64 * 4];    //  1 KB  dt_raw per pixel (half-line)

    const int t = threadIdx.x;
    const int half = blockIdx.x >> 9;
    const int r9 = blockIdx.x & 511;
    const int b = r9 >> 7;
    const int L = r9 & 127;
    const int wv = t >> 6, lane = t & 63;

    // ---- scan-role constants; h-state persists across both segments ----
    const int d = t >> 2, ng = t & 3, n0 = ng * 4;
    const float A0 = -__expf(A_log[d * NN + n0 + 0]);
    const float A1 = -__expf(A_log[d * NN + n0 + 1]);
    const float A2 = -__expf(A_log[d * NN + n0 + 2]);
    const float A3 = -__expf(A_log[d * NN + n0 + 3]);
    const float Dd = Dv[d];
    const float4 wt4 = *(const float4*)&dtw[d * 4];
    const float bdd = dtb[d];
    float h0 = 0.f, h1 = 0.f, h2 = 0.f, h3 = 0.f;
    float* drow = (half == 0 ? out : yv) + ((size_t)(b * CC + d) * 128 + L) * 128;

    const int p0 = __builtin_amdgcn_readfirstlane(wv * 9);

    for (int seg = 0; seg < 2; ++seg) {
        if (seg) __syncthreads();                // all seg-0 LDS reads done

        // ---- stage 64-pixel half-line into swizzled xt ----
        if (half == 0) {
#pragma unroll
            for (int k = 0; k < 4; ++k) {        // rows: float4 coalesced
                int i = k * 256 + t;
                int c = i >> 4, j0 = (i & 15) * 4;
                float4 v = *(const float4*)&x[((size_t)(b * CC + c) * HH + L) * WW
                                              + seg * 64 + j0];
                xt[(j0 + 0) * 64 + ((c + j0 + 0) & 63)] = v.x;
                xt[(j0 + 1) * 64 + ((c + j0 + 1) & 63)] = v.y;
                xt[(j0 + 2) * 64 + ((c + j0 + 2) & 63)] = v.z;
                xt[(j0 + 3) * 64 + ((c + j0 + 3) & 63)] = v.w;
            }
        } else {
#pragma unroll
            for (int p = 0; p < 16; ++p) {       // cols: L2/L3-served gather
                int jl = p * 4 + wv;
                xt[jl * 64 + ((lane + jl) & 63)] =
                    x[((size_t)(b * CC + lane) * HH + seg * 64 + jl) * WW + L];
            }
        }
        __syncthreads();

        // ---- proj: each wave does 9 of 36 cols for all 64 pixels ----
        {
            const int pix = lane, sw = pix & 7;
            const float* xw = xpw + p0 * CC;     // wave-uniform -> s_load path
            float acc[9];
#pragma unroll
            for (int j = 0; j < 9; ++j) acc[j] = 0.f;
            for (int c4 = 0; c4 < 16; ++c4) {
                float xv0 = xt[pix * 64 + ((c4 * 4 + 0 + pix) & 63)];
                float xv1 = xt[pix * 64 + ((c4 * 4 + 1 + pix) & 63)];
                float xv2 = xt[pix * 64 + ((c4 * 4 + 2 + pix) & 63)];
                float xv3 = xt[pix * 64 + ((c4 * 4 + 3 + pix) & 63)];
#pragma unroll
                for (int j = 0; j < 9; ++j) {
                    float4 wq = *(const float4*)&xw[j * CC + c4 * 4];
                    acc[j] = fmaf(wq.x, xv0, fmaf(wq.y, xv1,
                             fmaf(wq.z, xv2, fmaf(wq.w, xv3, acc[j]))));
                }
            }
            float* bp = &bcs[pix * 32];
            if (wv == 0) {          // cols 0-8: dt_raw + B0..4
                *(float4*)&dtr[pix * 4] = make_float4(acc[0], acc[1], acc[2], acc[3]);
                *(float4*)&bp[((0 ^ sw) << 2)] = make_float4(acc[4], acc[5], acc[6], acc[7]);
                bp[((1 ^ sw) << 2) + 0] = acc[8];
            } else if (wv == 1) {   // cols 9-17: B5..13
                bp[((1 ^ sw) << 2) + 1] = acc[0];
                bp[((1 ^ sw) << 2) + 2] = acc[1];
                bp[((1 ^ sw) << 2) + 3] = acc[2];
                *(float4*)&bp[((2 ^ sw) << 2)] = make_float4(acc[3], acc[4], acc[5], acc[6]);
                bp[((3 ^ sw) << 2) + 0] = acc[7];
                bp[((3 ^ sw) << 2) + 1] = acc[8];
            } else if (wv == 2) {   // cols 18-26: B14,15 + C0..6
                bp[((3 ^ sw) << 2) + 2] = acc[0];
                bp[((3 ^ sw) << 2) + 3] = acc[1];
                *(float4*)&bp[((4 ^ sw) << 2)] = make_float4(acc[2], acc[3], acc[4], acc[5]);
                bp[((5 ^ sw) << 2) + 0] = acc[6];
                bp[((5 ^ sw) << 2) + 1] = acc[7];
                bp[((5 ^ sw) << 2) + 2] = acc[8];
            } else {                // cols 27-35: C7..15
                bp[((5 ^ sw) << 2) + 3] = acc[0];
                *(float4*)&bp[((6 ^ sw) << 2)] = make_float4(acc[1], acc[2], acc[3], acc[4]);
                *(float4*)&bp[((7 ^ sw) << 2)] = make_float4(acc[5], acc[6], acc[7], acc[8]);
            }
        }
        __syncthreads();

        // ---- 8 chunks x 8 scan steps, barrier-free ----
        // jj = ch*8+JL is local; jj&7 == JL (compile-time swizzle select).
#define SCAN_STEP(JL, DSRC)                                                    \
        {                                                                      \
            float delta = quad_bcast<(JL) & 3>(DSRC);                          \
            const int jj = ch * 8 + (JL);                                      \
            float u = xt[jj * 64 + ((d + jj) & 63)];                           \
            float4 Bv = *(const float4*)&bcs[jj * 32 + ((ng ^ (JL)) << 2)];    \
            float4 Cv = *(const float4*)&bcs[jj * 32 + (((4 + ng) ^ (JL)) << 2)]; \
            float du = delta * u;                                              \
            h0 = fmaf(__expf(delta * A0), h0, du * Bv.x);                      \
            h1 = fmaf(__expf(delta * A1), h1, du * Bv.y);                      \
            h2 = fmaf(__expf(delta * A2), h2, du * Bv.z);                      \
            h3 = fmaf(__expf(delta * A3), h3, du * Bv.w);                      \
            float y = fmaf(h0, Cv.x, fmaf(h1, Cv.y, fmaf(h2, Cv.z, h3 * Cv.w))); \
            y += __shfl_xor(y, 1);                                             \
            y += __shfl_xor(y, 2);                                             \
            y = fmaf(u, Dd, y);                                                \
            if (ng == ((JL) >> 1)) { if ((JL) & 1) y1 = y; else y0 = y; }      \
        }

        for (int ch = 0; ch < 8; ++ch) {
            // quad-parallel delta: quad-lane ng owns steps jl=ng and jl=ng+4
            float4 drA = *(const float4*)&dtr[(ch * 8 + ng) * 4];
            float4 drB = *(const float4*)&dtr[(ch * 8 + 4 + ng) * 4];
            float da = softplus_f(fmaf(drA.x, wt4.x, fmaf(drA.y, wt4.y,
                       fmaf(drA.z, wt4.z, fmaf(drA.w, wt4.w, bdd)))));
            float db = softplus_f(fmaf(drB.x, wt4.x, fmaf(drB.y, wt4.y,
                       fmaf(drB.z, wt4.z, fmaf(drB.w, wt4.w, bdd)))));
            float y0 = 0.f, y1 = 0.f;
            SCAN_STEP(0, da) SCAN_STEP(1, da) SCAN_STEP(2, da) SCAN_STEP(3, da)
            SCAN_STEP(4, db) SCAN_STEP(5, db) SCAN_STEP(6, db) SCAN_STEP(7, db)
            *(float2*)&drow[seg * 64 + ch * 8 + ng * 2] = make_float2(y0, y1);
        }
#undef SCAN_STEP
    }
}

// ===========================================================================
// out[b,c,h,w] += yv[b,c,w,h]  (32x32 LDS-tile transposed RMW). R11-proven.
// ===========================================================================
__global__ __launch_bounds__(256) void k_add(const float* __restrict__ yv,
                                             float* __restrict__ out)
{
    __shared__ float td[32 * 33];
    int t = threadIdx.x;
    int bc_ = blockIdx.x >> 4;
    int tb = blockIdx.x & 15;
    int w0 = (tb & 3) * 32;
    int h0 = (tb >> 2) * 32;
    const float* src = yv + (size_t)bc_ * HW;   // [w][h]
    float* dst = out + (size_t)bc_ * HW;        // [h][w]
    int r = t >> 3, q = t & 7;
    float4 v = *(const float4*)&src[(w0 + r) * HH + h0 + q * 4];
    td[r * 33 + q * 4 + 0] = v.x;
    td[r * 33 + q * 4 + 1] = v.y;
    td[r * 33 + q * 4 + 2] = v.z;
    td[r * 33 + q * 4 + 3] = v.w;
    __syncthreads();
    float* op = &dst[(h0 + r) * WW + w0 + q * 4];
    float4 o = *(float4*)op;
    o.x += td[(q * 4 + 0) * 33 + r];
    o.y += td[(q * 4 + 1) * 33 + r];
    o.z += td[(q * 4 + 2) * 33 + r];
    o.w += td[(q * 4 + 3) * 33 + r];
    *(float4*)op = o;
}

// ---------------------------------------------------------------------------
extern "C" void kernel_launch(void* const* d_in, const int* in_sizes, int n_in,
                              void* d_out, int out_size, void* d_ws, size_t ws_size,
                              hipStream_t stream) {
    const float* x     = (const float*)d_in[0];
    const float* A_log = (const float*)d_in[1];
    const float* Dv    = (const float*)d_in[2];
    const float* xpw   = (const float*)d_in[3];
    const float* dtw   = (const float*)d_in[4];
    const float* dtb   = (const float*)d_in[5];
    float* out = (float*)d_out;
    float* yv  = (float*)d_ws;       // 16.8 MB; ws >= 43 MB proven in R11

    k_scan<<<1024, 256, 0, stream>>>(x, xpw, A_log, Dv, dtw, dtb, out, yv);
    k_add <<<BB * CC * 16, 256, 0, stream>>>(yv, out);
}